// Round 9
// baseline (730.760 us; speedup 1.0000x reference)
//
#include <hip/hip_runtime.h>
#include <hip/hip_bf16.h>
#include <stdint.h>

#define SEQLEN 512
#define NBATCH 64
#define KDIM   512
#define HDIM   1024
#define MTOT   (SEQLEN * NBATCH)   // 32768
#define NTOT   (3 * HDIM)          // 3072
#define STRIDE (NBATCH * HDIM)     // 65536

typedef __attribute__((ext_vector_type(4))) float f32x4;
typedef _Float16 f16x8 __attribute__((ext_vector_type(8)));

// ---------- conversion: fp32 -> (hi, lo) fp16 split planes ---------------
// 3-pass MFMA (AhBh+AhBl+AlBh) ~= fp32 GEMM (r5: 2-pass fails at 0.51).
__global__ __launch_bounds__(256) void cvt_x(const float* __restrict__ x,
                                             _Float16* __restrict__ xh,
                                             _Float16* __restrict__ xl) {
    int i = blockIdx.x * 256 + threadIdx.x;
    const float4* s = (const float4*)(x + (size_t)i * 8);
    float4 a = s[0], b = s[1];
    float v[8] = {a.x, a.y, a.z, a.w, b.x, b.y, b.z, b.w};
    f16x8 hi, lo;
#pragma unroll
    for (int j = 0; j < 8; ++j) {
        _Float16 h = (_Float16)v[j];
        hi[j] = h;
        lo[j] = (_Float16)(v[j] - (float)h);
    }
    *(f16x8*)(xh + (size_t)i * 8) = hi;
    *(f16x8*)(xl + (size_t)i * 8) = lo;
}

__global__ __launch_bounds__(256) void cvt_u(const float* __restrict__ Uc,
                                             const float* __restrict__ Ua,
                                             const float* __restrict__ Uh,
                                             _Float16* __restrict__ uh,
                                             _Float16* __restrict__ ul) {
    int i = blockIdx.x * 256 + threadIdx.x;
    int n = i >> 6;
    int kb = (i & 63) * 8;
    const float* src = (n < HDIM) ? (Uc + (size_t)n * KDIM)
                     : (n < 2 * HDIM) ? (Ua + (size_t)(n - HDIM) * KDIM)
                     : (Uh + (size_t)(n - 2 * HDIM) * KDIM);
    const float4* s = (const float4*)(src + kb);
    float4 a = s[0], b = s[1];
    float v[8] = {a.x, a.y, a.z, a.w, b.x, b.y, b.z, b.w};
    f16x8 hi, lo;
#pragma unroll
    for (int j = 0; j < 8; ++j) {
        _Float16 h = (_Float16)v[j];
        hi[j] = h;
        lo[j] = (_Float16)(v[j] - (float)h);
    }
    *(f16x8*)(uh + (size_t)n * KDIM + kb) = hi;
    *(f16x8*)(ul + (size_t)n * KDIM + kb) = lo;
}

// --------- GEMM: proj[M][3072] = (Xh+Xl)·(Uh+Ul)^T, 3-pass split ---------
// Round-9: 256x384 tile (wave tile 128x96: LDS-read:MFMA ratio -22% vs
// 256x256), BK=32, 512 thr = 8 waves (2M x 4N), 16x16x32 MFMA (r8's 32x32
// regressed: conflicts returned), 160 KB double-buffered LDS (HW max),
// r6 relaxed schedule: ONE raw barrier + per-wave vmcnt(0) per K-tile,
// stages spread mid-body, T2 chunk-XOR swizzle (0 conflicts, r3-r7).
#define BM 256
#define BN 384
#define BK 32
#define NT_N (NTOT / BN)            // 8
#define GRID ((MTOT / BM) * NT_N)   // 1024
#define KT_N (KDIM / BK)            // 16
// halfword offsets within one LDS buffer (A: 256 rows, B: 384 rows, x32 k)
#define OFF_AH 0
#define OFF_AL 8192
#define OFF_BH 16384
#define OFF_BL 28672
#define BUF_HW 40960                 // 80 KB per buffer, 160 KB total

__device__ __forceinline__ void gload16(const _Float16* g, _Float16* l) {
    __builtin_amdgcn_global_load_lds((const __attribute__((address_space(1))) void*)g,
                                     (__attribute__((address_space(3))) void*)l,
                                     16, 0, 0);
}

__device__ __forceinline__ f32x4 mfma16(f16x8 a, f16x8 b, f32x4 c) {
    return __builtin_amdgcn_mfma_f32_16x16x32_f16(a, b, c, 0, 0, 0);
}

__global__ __launch_bounds__(512, 2) void gemm_f16x2(const _Float16* __restrict__ Ah,
                                                     const _Float16* __restrict__ Al,
                                                     const _Float16* __restrict__ Bh,
                                                     const _Float16* __restrict__ Bl,
                                                     float* __restrict__ pc,
                                                     float* __restrict__ pa,
                                                     float* __restrict__ ph) {
    __shared__ _Float16 lds[2][BUF_HW];   // 163840 B

    int bid  = blockIdx.x;          // default order, A-panel-major
    int bm   = bid / NT_N;
    int bn   = bid % NT_N;
    int tid  = threadIdx.x;
    int lane = tid & 63;
    int wave = tid >> 6;
    int wr   = wave >> 2;           // 0..1 (M half, 128 rows)
    int wc   = wave & 3;            // 0..3 (N quarter, 96 cols)

    // staging (T2 source-side chunk permute; measured conflict-free r3-r7)
    size_t row_off = (size_t)(tid >> 2) * KDIM
                   + (size_t)(((tid & 3) ^ ((tid >> 3) & 3)) * 8);
    const _Float16* gAh = Ah + (size_t)bm * BM * KDIM + row_off;
    const _Float16* gAl = Al + (size_t)bm * BM * KDIM + row_off;
    const _Float16* gBh = Bh + (size_t)bn * BN * KDIM + row_off;
    const _Float16* gBl = Bl + (size_t)bn * BN * KDIM + row_off;
    const size_t P128 = (size_t)128 * KDIM;   // +128 rows in global
    int t8 = tid * 8;

// A plane: 256 rows = 2 gloads; B plane: 384 rows = 3 gloads.
#define SA(buf, off, gp, kt) do { int _g = (kt) * BK;                          \
    gload16((gp) + _g,            &lds[buf][(off) + t8]);                      \
    gload16((gp) + P128 + _g,     &lds[buf][(off) + 4096 + t8]); } while (0)
#define SB(buf, off, gp, kt) do { int _g = (kt) * BK;                          \
    gload16((gp) + _g,            &lds[buf][(off) + t8]);                      \
    gload16((gp) + P128 + _g,     &lds[buf][(off) + 4096 + t8]);               \
    gload16((gp) + 2 * P128 + _g, &lds[buf][(off) + 8192 + t8]); } while (0)

    f32x4 acc[8][6];
#pragma unroll
    for (int i = 0; i < 8; ++i)
#pragma unroll
        for (int j = 0; j < 6; ++j)
            acc[i][j] = (f32x4){0.f, 0.f, 0.f, 0.f};

    int ro = lane & 15;
    int ko = ((lane >> 4) ^ ((lane >> 1) & 3)) * 8;   // read-side swizzle

    f16x8 a0_[4][2], a1_[4][2], b_[6][2];

#define READ_A(arr, mh) _Pragma("unroll")                                      \
    for (int i = 0; i < 4; ++i) {                                              \
        int row = wr * 128 + ((mh) * 4 + i) * 16 + ro;                         \
        arr[i][0] = *(const f16x8*)(&lds[cur][OFF_AH + row * BK + ko]);        \
        arr[i][1] = *(const f16x8*)(&lds[cur][OFF_AL + row * BK + ko]);        \
    }
#define READ_B() _Pragma("unroll")                                             \
    for (int j = 0; j < 6; ++j) {                                              \
        int row = wc * 96 + j * 16 + ro;                                       \
        b_[j][0] = *(const f16x8*)(&lds[cur][OFF_BH + row * BK + ko]);         \
        b_[j][1] = *(const f16x8*)(&lds[cur][OFF_BL + row * BK + ko]);         \
    }
#define MFMA_HALF(arr, mh) _Pragma("unroll")                                   \
    for (int i = 0; i < 4; ++i) _Pragma("unroll")                              \
        for (int j = 0; j < 6; ++j) {                                          \
            f32x4 c = acc[(mh) * 4 + i][j];                                    \
            c = mfma16(arr[i][0], b_[j][1], c);   /* Ah·Bl */                  \
            c = mfma16(arr[i][1], b_[j][0], c);   /* Al·Bh */                  \
            c = mfma16(arr[i][0], b_[j][0], c);   /* Ah·Bh */                  \
            acc[(mh) * 4 + i][j] = c;                                          \
        }

    // prologue: tile 0 -> buf 0 (10 loads)
    SA(0, OFF_AH, gAh, 0); SA(0, OFF_AL, gAl, 0);
    SB(0, OFF_BH, gBh, 0); SB(0, OFF_BL, gBl, 0);

    for (int kt = 0; kt < KT_N; ++kt) {
        int cur = kt & 1, nxt = 1 - cur;
        bool pre = (kt < KT_N - 1);
        __builtin_amdgcn_sched_barrier(0);
        asm volatile("s_waitcnt vmcnt(0)" ::: "memory");
        __builtin_amdgcn_s_barrier();
        __builtin_amdgcn_sched_barrier(0);

        READ_B();
        READ_A(a0_, 0);
        if (pre) { SA(nxt, OFF_AH, gAh, kt + 1); SA(nxt, OFF_AL, gAl, kt + 1); }
        __builtin_amdgcn_s_setprio(1);
        MFMA_HALF(a0_, 0);
        __builtin_amdgcn_s_setprio(0);
        READ_A(a1_, 1);
        if (pre) { SB(nxt, OFF_BH, gBh, kt + 1); SB(nxt, OFF_BL, gBl, kt + 1); }
        __builtin_amdgcn_s_setprio(1);
        MFMA_HALF(a1_, 1);
        __builtin_amdgcn_s_setprio(0);
    }

    // epilogue: D col=lane&15 (N), row=(lane>>4)*4+r (M)  [m89-verified]
    // BN=384 tiles straddle pc/pa/ph boundaries -> route per 16-col j-tile
    // (16-col tiles never straddle: 1024 % 16 == 0).
#pragma unroll
    for (int j = 0; j < 6; ++j) {
        int ntb = bn * BN + wc * 96 + j * 16;   // tile base, multiple of 16
        float* outp = (ntb < HDIM) ? pc : (ntb < 2 * HDIM) ? pa : ph;
        int nb = ntb & (HDIM - 1);
        int n = nb + (lane & 15);
#pragma unroll
        for (int ai = 0; ai < 8; ++ai) {
            int m = bm * BM + wr * 128 + ai * 16 + (lane >> 4) * 4;
#pragma unroll
            for (int r = 0; r < 4; ++r)
                outp[(size_t)(m + r) * HDIM + n] = acc[ai][j][r];
        }
    }
#undef SA
#undef SB
#undef READ_A
#undef READ_B
#undef MFMA_HALF
}

// ------------------------- recurrence ------------------------------------
// one thread per (b,j); 65536 threads; depth-16 register prefetch pipeline
// (PF=16: 48 outstanding loads <= 63 vmcnt capacity; PF=32 exceeded it).
// libm transcendentals (r8 measured: fast variants null — BW/latency-bound).
__global__ __launch_bounds__(256) void recur(const float* __restrict__ pc_a,
                                             const float* __restrict__ pa_a,
                                             float* out,
                                             const float* __restrict__ h0,
                                             const float* __restrict__ wc_,
                                             const float* __restrict__ bc_,
                                             const float* __restrict__ wa_,
                                             const float* __restrict__ ba_,
                                             const float* __restrict__ bh_) {
    int idx = blockIdx.x * 256 + threadIdx.x;
    int j = idx & (HDIM - 1);
    float h  = h0[idx];
    float wc = wc_[j], bc = bc_[j];
    float wa = wa_[j], ba = ba_[j];
    float bh = bh_[j];

#define PF 16
    float pc[PF], pa[PF], ph[PF];
#pragma unroll
    for (int u = 0; u < PF; ++u) {
        pc[u] = pc_a[(size_t)u * STRIDE + idx];
        pa[u] = pa_a[(size_t)u * STRIDE + idx];
        ph[u] = out [(size_t)u * STRIDE + idx];
    }

    for (int sb = 0; sb < SEQLEN; sb += PF) {
#pragma unroll
        for (int u = 0; u < PF; ++u) {
            int s = sb + u;
            float vc = pc[u], va = pa[u], vh = ph[u];
            int sp = s + PF; sp = (sp < SEQLEN) ? sp : (SEQLEN - 1);
            pc[u] = pc_a[(size_t)sp * STRIDE + idx];
            pa[u] = pa_a[(size_t)sp * STRIDE + idx];
            ph[u] = out [(size_t)sp * STRIDE + idx];

            float zc = (vc + bc) + wc * h;
            float za = (va + ba) + wa * h;
            float c  = 1.0f / (1.0f + expf(-zc));
            float a  = 1.0f + tanhf(za);
            float ht = tanhf((vh + bh) + a * h);
            h = c * h + (1.0f - c) * ht;
            out[(size_t)s * STRIDE + idx] = h;
        }
    }
    out[(size_t)SEQLEN * STRIDE + idx] = h;   // hn
}

// --------------------------- launch --------------------------------------
extern "C" void kernel_launch(void* const* d_in, const int* in_sizes, int n_in,
                              void* d_out, int out_size, void* d_ws, size_t ws_size,
                              hipStream_t stream) {
    const float* x_seq = (const float*)d_in[0];
    const float* h0    = (const float*)d_in[1];
    const float* U_c   = (const float*)d_in[2];
    const float* w_c   = (const float*)d_in[3];
    const float* b_c   = (const float*)d_in[4];
    const float* U_a   = (const float*)d_in[5];
    const float* w_a   = (const float*)d_in[6];
    const float* b_a   = (const float*)d_in[7];
    const float* U_h   = (const float*)d_in[8];
    const float* b_h   = (const float*)d_in[9];
    float* out = (float*)d_out;

    char* ws = (char*)d_ws;
    const size_t MB = 1024 * 1024;
    float*    ws_pc = (float*)ws;                        // 128 MB
    float*    ws_pa = (float*)(ws + 128 * MB);           // 128 MB
    _Float16* x_hi  = (_Float16*)(ws + 256 * MB);        // 32 MB
    _Float16* x_lo  = (_Float16*)(ws + 288 * MB);        // 32 MB
    _Float16* u_hi  = (_Float16*)(ws + 320 * MB);        // 3 MB
    _Float16* u_lo  = (_Float16*)(ws + 323 * MB);        // 3 MB

    cvt_x<<<dim3(MTOT * KDIM / 8 / 256), dim3(256), 0, stream>>>(x_seq, x_hi, x_lo);
    cvt_u<<<dim3(NTOT * KDIM / 8 / 256), dim3(256), 0, stream>>>(U_c, U_a, U_h, u_hi, u_lo);
    gemm_f16x2<<<dim3(GRID), dim3(512), 0, stream>>>(
        x_hi, x_lo, u_hi, u_lo, ws_pc, ws_pa, out);
    recur<<<dim3(STRIDE / 256), dim3(256), 0, stream>>>(ws_pc, ws_pa, out, h0,
                                                        w_c, b_c, w_a, b_a, b_h);
}

// Round 10
// 514.739 us; speedup vs baseline: 1.4197x; 1.4197x over previous
//
#include <hip/hip_runtime.h>
#include <hip/hip_bf16.h>
#include <stdint.h>

#define SEQLEN 512
#define NBATCH 64
#define KDIM   512
#define HDIM   1024
#define MTOT   (SEQLEN * NBATCH)   // 32768
#define NTOT   (3 * HDIM)          // 3072
#define STRIDE (NBATCH * HDIM)     // 65536

typedef __attribute__((ext_vector_type(4))) float f32x4;
typedef _Float16 f16x8 __attribute__((ext_vector_type(8)));

// ---------- conversion: fp32 -> (hi, lo) fp16 split planes ---------------
// 3-pass MFMA (AhBh+AhBl+AlBh) ~= fp32 GEMM (r5: 2-pass fails at 0.51).
__global__ __launch_bounds__(256) void cvt_x(const float* __restrict__ x,
                                             _Float16* __restrict__ xh,
                                             _Float16* __restrict__ xl) {
    int i = blockIdx.x * 256 + threadIdx.x;
    const float4* s = (const float4*)(x + (size_t)i * 8);
    float4 a = s[0], b = s[1];
    float v[8] = {a.x, a.y, a.z, a.w, b.x, b.y, b.z, b.w};
    f16x8 hi, lo;
#pragma unroll
    for (int j = 0; j < 8; ++j) {
        _Float16 h = (_Float16)v[j];
        hi[j] = h;
        lo[j] = (_Float16)(v[j] - (float)h);
    }
    *(f16x8*)(xh + (size_t)i * 8) = hi;
    *(f16x8*)(xl + (size_t)i * 8) = lo;
}

__global__ __launch_bounds__(256) void cvt_u(const float* __restrict__ Uc,
                                             const float* __restrict__ Ua,
                                             const float* __restrict__ Uh,
                                             _Float16* __restrict__ uh,
                                             _Float16* __restrict__ ul) {
    int i = blockIdx.x * 256 + threadIdx.x;
    int n = i >> 6;
    int kb = (i & 63) * 8;
    const float* src = (n < HDIM) ? (Uc + (size_t)n * KDIM)
                     : (n < 2 * HDIM) ? (Ua + (size_t)(n - HDIM) * KDIM)
                     : (Uh + (size_t)(n - 2 * HDIM) * KDIM);
    const float4* s = (const float4*)(src + kb);
    float4 a = s[0], b = s[1];
    float v[8] = {a.x, a.y, a.z, a.w, b.x, b.y, b.z, b.w};
    f16x8 hi, lo;
#pragma unroll
    for (int j = 0; j < 8; ++j) {
        _Float16 h = (_Float16)v[j];
        hi[j] = h;
        lo[j] = (_Float16)(v[j] - (float)h);
    }
    *(f16x8*)(uh + (size_t)n * KDIM + kb) = hi;
    *(f16x8*)(ul + (size_t)n * KDIM + kb) = lo;
}

// --------- GEMM: proj[M][3072] = (Xh+Xl)·(Uh+Ul)^T, 3-pass split ---------
// Round-10: T4 counted-vmcnt, never-drain. 256x128 tile, BK=32, 512 thr =
// 8 waves (4M x 2N, wave-tile 64x64), TRIPLE-buffered 144 KB LDS (48 KB/buf).
// Steady state: body kt reads buf[kt%3], stages kt+2 into the buffer freed
// at the last barrier; boundary wait = vmcnt(6) (only stage(kt+1)'s 6 loads
// stay in flight) -> the wait targets loads issued TWO bodies ago, ~instant.
// Epilogue: ai-outer/j-inner (r9 lesson: j-outer caused 3.7x write amplif).
#define BM 256
#define BN 128
#define BK 32
#define NT_N (NTOT / BN)            // 24
#define GRID ((MTOT / BM) * NT_N)   // 3072
#define KT_N (KDIM / BK)            // 16
// halfword offsets within one 48 KB buffer
#define OFF_AH 0
#define OFF_AL 8192
#define OFF_BH 16384
#define OFF_BL 20480
#define BUF_HW 24576

__device__ __forceinline__ void gload16(const _Float16* g, _Float16* l) {
    __builtin_amdgcn_global_load_lds((const __attribute__((address_space(1))) void*)g,
                                     (__attribute__((address_space(3))) void*)l,
                                     16, 0, 0);
}

__device__ __forceinline__ f32x4 mfma16(f16x8 a, f16x8 b, f32x4 c) {
    return __builtin_amdgcn_mfma_f32_16x16x32_f16(a, b, c, 0, 0, 0);
}

__global__ __launch_bounds__(512, 2) void gemm_f16x2(const _Float16* __restrict__ Ah,
                                                     const _Float16* __restrict__ Al,
                                                     const _Float16* __restrict__ Bh,
                                                     const _Float16* __restrict__ Bl,
                                                     float* __restrict__ pc,
                                                     float* __restrict__ pa,
                                                     float* __restrict__ ph) {
    __shared__ _Float16 lds[3][BUF_HW];   // 147456 B

    int bid  = blockIdx.x;          // default order, A-panel-major
    int bm   = bid / NT_N;
    int bn   = bid % NT_N;
    int tid  = threadIdx.x;
    int lane = tid & 63;
    int wave = tid >> 6;
    int wr   = wave >> 1;           // 0..3 (M quarter, 64 rows)
    int wc   = wave & 1;            // 0..1 (N half, 64 cols)

    // staging (T2 source-side chunk permute; measured conflict-free r3-r7)
    size_t row_off = (size_t)(tid >> 2) * KDIM
                   + (size_t)(((tid & 3) ^ ((tid >> 3) & 3)) * 8);
    const _Float16* gAh = Ah + (size_t)bm * BM * KDIM + row_off;
    const _Float16* gAl = Al + (size_t)bm * BM * KDIM + row_off;
    const _Float16* gBh = Bh + (size_t)bn * BN * KDIM + row_off;
    const _Float16* gBl = Bl + (size_t)bn * BN * KDIM + row_off;
    const size_t P128 = (size_t)128 * KDIM;   // +128 rows in global
    int t8 = tid * 8;

// 6 loads per tile: A planes 2 each (256 rows), B planes 1 each (128 rows)
#define STAGE(buf, kt) do { int _g = (kt) * BK;                                \
    gload16(gAh + _g,        &lds[buf][OFF_AH + t8]);                          \
    gload16(gAh + P128 + _g, &lds[buf][OFF_AH + 4096 + t8]);                   \
    gload16(gAl + _g,        &lds[buf][OFF_AL + t8]);                          \
    gload16(gAl + P128 + _g, &lds[buf][OFF_AL + 4096 + t8]);                   \
    gload16(gBh + _g,        &lds[buf][OFF_BH + t8]);                          \
    gload16(gBl + _g,        &lds[buf][OFF_BL + t8]); } while (0)

    f32x4 acc[4][4];
#pragma unroll
    for (int i = 0; i < 4; ++i)
#pragma unroll
        for (int j = 0; j < 4; ++j)
            acc[i][j] = (f32x4){0.f, 0.f, 0.f, 0.f};

    int ro = lane & 15;
    int ko = ((lane >> 4) ^ ((lane >> 1) & 3)) * 8;   // read-side swizzle

    f16x8 a_[4][2], b_[4][2];

#define READ_A(cb) _Pragma("unroll")                                           \
    for (int i = 0; i < 4; ++i) {                                              \
        int row = wr * 64 + i * 16 + ro;                                       \
        a_[i][0] = *(const f16x8*)(&lds[cb][OFF_AH + row * BK + ko]);          \
        a_[i][1] = *(const f16x8*)(&lds[cb][OFF_AL + row * BK + ko]);          \
    }
#define READ_B(cb) _Pragma("unroll")                                           \
    for (int j = 0; j < 4; ++j) {                                              \
        int row = wc * 64 + j * 16 + ro;                                       \
        b_[j][0] = *(const f16x8*)(&lds[cb][OFF_BH + row * BK + ko]);          \
        b_[j][1] = *(const f16x8*)(&lds[cb][OFF_BL + row * BK + ko]);          \
    }
#define MFMA_ALL() _Pragma("unroll")                                           \
    for (int i = 0; i < 4; ++i) _Pragma("unroll")                              \
        for (int j = 0; j < 4; ++j) {                                          \
            f32x4 c = acc[i][j];                                               \
            c = mfma16(a_[i][0], b_[j][1], c);   /* Ah·Bl */                   \
            c = mfma16(a_[i][1], b_[j][0], c);   /* Al·Bh */                   \
            c = mfma16(a_[i][0], b_[j][0], c);   /* Ah·Bh */                   \
            acc[i][j] = c;                                                     \
        }

    // prologue: tiles 0,1 -> buffers 0,1 (12 loads in flight)
    STAGE(0, 0);
    STAGE(1, 1);

    int c0 = 0, c1 = 1, c2 = 2;     // c0 = read, c2 = stage target
    for (int kt = 0; kt < KT_N; ++kt) {
        __builtin_amdgcn_sched_barrier(0);
        if (kt < KT_N - 1) asm volatile("s_waitcnt vmcnt(6)" ::: "memory");
        else               asm volatile("s_waitcnt vmcnt(0)" ::: "memory");
        __builtin_amdgcn_s_barrier();
        __builtin_amdgcn_sched_barrier(0);

        READ_B(c0);
        READ_A(c0);
        if (kt + 2 < KT_N) STAGE(c2, kt + 2);   // buffer freed at last barrier
        __builtin_amdgcn_s_setprio(1);
        MFMA_ALL();
        __builtin_amdgcn_s_setprio(0);

        int t = c0; c0 = c1; c1 = c2; c2 = t;
    }

    // epilogue: D col=lane&15 (N), row=(lane>>4)*4+r (M)  [m89-verified]
    // BN=128 divides HDIM -> whole block routes to one output buffer.
    int n0 = bn * BN;
    float* outp = (n0 < HDIM) ? pc : (n0 < 2 * HDIM) ? pa : ph;
    int nb = n0 & (HDIM - 1);
#pragma unroll
    for (int i = 0; i < 4; ++i)
#pragma unroll
        for (int r = 0; r < 4; ++r) {
            int m = bm * BM + wr * 64 + i * 16 + (lane >> 4) * 4 + r;
#pragma unroll
            for (int j = 0; j < 4; ++j) {       // N-inner: line-friendly
                int n = nb + wc * 64 + j * 16 + (lane & 15);
                outp[(size_t)m * HDIM + n] = acc[i][j][r];
            }
        }
#undef STAGE
#undef READ_A
#undef READ_B
#undef MFMA_ALL
}

// ------------------------- recurrence ------------------------------------
// one thread per (b,j); 65536 threads; depth-16 register prefetch pipeline
// (PF=16: 48 outstanding loads <= 63 vmcnt capacity; PF=32 exceeded it).
// libm transcendentals (r8 measured: fast variants null — BW/latency-bound).
__global__ __launch_bounds__(256) void recur(const float* __restrict__ pc_a,
                                             const float* __restrict__ pa_a,
                                             float* out,
                                             const float* __restrict__ h0,
                                             const float* __restrict__ wc_,
                                             const float* __restrict__ bc_,
                                             const float* __restrict__ wa_,
                                             const float* __restrict__ ba_,
                                             const float* __restrict__ bh_) {
    int idx = blockIdx.x * 256 + threadIdx.x;
    int j = idx & (HDIM - 1);
    float h  = h0[idx];
    float wc = wc_[j], bc = bc_[j];
    float wa = wa_[j], ba = ba_[j];
    float bh = bh_[j];

#define PF 16
    float pc[PF], pa[PF], ph[PF];
#pragma unroll
    for (int u = 0; u < PF; ++u) {
        pc[u] = pc_a[(size_t)u * STRIDE + idx];
        pa[u] = pa_a[(size_t)u * STRIDE + idx];
        ph[u] = out [(size_t)u * STRIDE + idx];
    }

    for (int sb = 0; sb < SEQLEN; sb += PF) {
#pragma unroll
        for (int u = 0; u < PF; ++u) {
            int s = sb + u;
            float vc = pc[u], va = pa[u], vh = ph[u];
            int sp = s + PF; sp = (sp < SEQLEN) ? sp : (SEQLEN - 1);
            pc[u] = pc_a[(size_t)sp * STRIDE + idx];
            pa[u] = pa_a[(size_t)sp * STRIDE + idx];
            ph[u] = out [(size_t)sp * STRIDE + idx];

            float zc = (vc + bc) + wc * h;
            float za = (va + ba) + wa * h;
            float c  = 1.0f / (1.0f + expf(-zc));
            float a  = 1.0f + tanhf(za);
            float ht = tanhf((vh + bh) + a * h);
            h = c * h + (1.0f - c) * ht;
            out[(size_t)s * STRIDE + idx] = h;
        }
    }
    out[(size_t)SEQLEN * STRIDE + idx] = h;   // hn
}

// --------------------------- launch --------------------------------------
extern "C" void kernel_launch(void* const* d_in, const int* in_sizes, int n_in,
                              void* d_out, int out_size, void* d_ws, size_t ws_size,
                              hipStream_t stream) {
    const float* x_seq = (const float*)d_in[0];
    const float* h0    = (const float*)d_in[1];
    const float* U_c   = (const float*)d_in[2];
    const float* w_c   = (const float*)d_in[3];
    const float* b_c   = (const float*)d_in[4];
    const float* U_a   = (const float*)d_in[5];
    const float* w_a   = (const float*)d_in[6];
    const float* b_a   = (const float*)d_in[7];
    const float* U_h   = (const float*)d_in[8];
    const float* b_h   = (const float*)d_in[9];
    float* out = (float*)d_out;

    char* ws = (char*)d_ws;
    const size_t MB = 1024 * 1024;
    float*    ws_pc = (float*)ws;                        // 128 MB
    float*    ws_pa = (float*)(ws + 128 * MB);           // 128 MB
    _Float16* x_hi  = (_Float16*)(ws + 256 * MB);        // 32 MB
    _Float16* x_lo  = (_Float16*)(ws + 288 * MB);        // 32 MB
    _Float16* u_hi  = (_Float16*)(ws + 320 * MB);        // 3 MB
    _Float16* u_lo  = (_Float16*)(ws + 323 * MB);        // 3 MB

    cvt_x<<<dim3(MTOT * KDIM / 8 / 256), dim3(256), 0, stream>>>(x_seq, x_hi, x_lo);
    cvt_u<<<dim3(NTOT * KDIM / 8 / 256), dim3(256), 0, stream>>>(U_c, U_a, U_h, u_hi, u_lo);
    gemm_f16x2<<<dim3(GRID), dim3(512), 0, stream>>>(
        x_hi, x_lo, u_hi, u_lo, ws_pc, ws_pa, out);
    recur<<<dim3(STRIDE / 256), dim3(256), 0, stream>>>(ws_pc, ws_pa, out, h0,
                                                        w_c, b_c, w_a, b_a, b_h);
}

// Round 11
// 493.718 us; speedup vs baseline: 1.4801x; 1.0426x over previous
//
#include <hip/hip_runtime.h>
#include <hip/hip_bf16.h>
#include <stdint.h>

#define SEQLEN 512
#define NBATCH 64
#define KDIM   512
#define HDIM   1024
#define MTOT   (SEQLEN * NBATCH)   // 32768
#define NTOT   (3 * HDIM)          // 3072
#define STRIDE (NBATCH * HDIM)     // 65536

typedef __attribute__((ext_vector_type(4)))  float f32x4;
typedef __attribute__((ext_vector_type(16))) float f32x16;
typedef _Float16 f16x8 __attribute__((ext_vector_type(8)));

// ---------- merged conversion: x and U -> (hi, lo) fp16 planes -----------
// 3-pass MFMA (AhBh+AhBl+AlBh) ~= fp32 GEMM (r5: 2-pass fails at 0.51).
#define XTHREADS (MTOT * KDIM / 8)   // 2,097,152
#define UTHREADS (NTOT * KDIM / 8)   //   196,608
__global__ __launch_bounds__(256) void cvt_all(const float* __restrict__ x,
                                               const float* __restrict__ Uc,
                                               const float* __restrict__ Ua,
                                               const float* __restrict__ Uh,
                                               _Float16* __restrict__ xh,
                                               _Float16* __restrict__ xl,
                                               _Float16* __restrict__ uh,
                                               _Float16* __restrict__ ul) {
    int i = blockIdx.x * 256 + threadIdx.x;
    const float* src;
    _Float16 *dh, *dl;
    size_t off;
    if (i < XTHREADS) {
        src = x + (size_t)i * 8;
        off = (size_t)i * 8;
        dh = xh; dl = xl;
    } else {
        int u = i - XTHREADS;
        int n = u >> 6;
        int kb = (u & 63) * 8;
        src = ((n < HDIM) ? (Uc + (size_t)n * KDIM)
             : (n < 2 * HDIM) ? (Ua + (size_t)(n - HDIM) * KDIM)
             : (Uh + (size_t)(n - 2 * HDIM) * KDIM)) + kb;
        off = (size_t)n * KDIM + kb;
        dh = uh; dl = ul;
    }
    const float4* s = (const float4*)src;
    float4 a = s[0], b = s[1];
    float v[8] = {a.x, a.y, a.z, a.w, b.x, b.y, b.z, b.w};
    f16x8 hi, lo;
#pragma unroll
    for (int j = 0; j < 8; ++j) {
        _Float16 h = (_Float16)v[j];
        hi[j] = h;
        lo[j] = (_Float16)(v[j] - (float)h);
    }
    *(f16x8*)(dh + off) = hi;
    *(f16x8*)(dl + off) = lo;
}

// --------- GEMM: proj[M][3072] = (Xh+Xl)·(Uh+Ul)^T, 3-pass split ---------
// Round-11: r6 relaxed schedule (best: 281us, one raw barrier + per-wave
// vmcnt(0) per K-tile, stages mid-body) + 32x32x16 MFMA (3100 vs 3725
// cyc/tile pipe content) + v2 swizzle fixing r8's 4-way conflict:
//   slot = chunk ^ ((row>>1)&3) ^ ((row>>3)&3)
// (r8's v1 used only row bits 1-2; rows {r,r+8,r+16,r+24} collided -> 1.9e7
// conflicts. v2 spreads all 32 rows uniformly: 8 lanes/bank-quad = clean.)
#define BM 256
#define BN 256
#define BK 32
#define NT_N (NTOT / BN)            // 12
#define GRID ((MTOT / BM) * NT_N)   // 1536
#define KT_N (KDIM / BK)            // 16

__device__ __forceinline__ void gload16(const _Float16* g, _Float16* l) {
    __builtin_amdgcn_global_load_lds((const __attribute__((address_space(1))) void*)g,
                                     (__attribute__((address_space(3))) void*)l,
                                     16, 0, 0);
}

__device__ __forceinline__ f32x16 mfma32(f16x8 a, f16x8 b, f32x16 c) {
    return __builtin_amdgcn_mfma_f32_32x32x16_f16(a, b, c, 0, 0, 0);
}

__global__ __launch_bounds__(512, 2) void gemm_f16x2(const _Float16* __restrict__ Ah,
                                                     const _Float16* __restrict__ Al,
                                                     const _Float16* __restrict__ Bh,
                                                     const _Float16* __restrict__ Bl,
                                                     float* __restrict__ pc,
                                                     float* __restrict__ pa,
                                                     float* __restrict__ ph) {
    // [buf][plane][256 rows * 32 f16]; plane 0=Ah 1=Al 2=Bh 3=Bl. 128 KB.
    __shared__ _Float16 lds[2][4][BM * BK];

    int bid  = blockIdx.x;          // default order, A-panel-major
    int bm   = bid / NT_N;
    int bn   = bid % NT_N;
    int tid  = threadIdx.x;
    int lane = tid & 63;
    int wave = tid >> 6;
    int wr   = wave >> 2;           // 0..1 (M half, 128 rows)
    int wc   = wave & 3;            // 0..3 (N quarter, 64 cols)

    // store-side v2 chunk permute: slot sc=tid&3 holds global chunk
    // gc = sc ^ ((row>>1)&3) ^ ((row>>3)&3), row = tid>>2
    //    = (tid&3) ^ ((tid>>3)&3) ^ ((tid>>5)&3)   [+128 rows: invariant]
    size_t row_off = (size_t)(tid >> 2) * KDIM
        + (size_t)((((tid & 3) ^ ((tid >> 3) & 3) ^ ((tid >> 5) & 3))) * 8);
    const _Float16* gAh = Ah + (size_t)bm * BM * KDIM + row_off;
    const _Float16* gAl = Al + (size_t)bm * BM * KDIM + row_off;
    const _Float16* gBh = Bh + (size_t)bn * BN * KDIM + row_off;
    const _Float16* gBl = Bl + (size_t)bn * BN * KDIM + row_off;
    const size_t P128 = (size_t)128 * KDIM;   // +128 rows in global
    int t8 = tid * 8;

#define SPAIR(buf, plane, gp, kt) do { int _g = (kt) * BK;                     \
    gload16((gp) + _g,        &lds[buf][plane][t8]);                           \
    gload16((gp) + P128 + _g, &lds[buf][plane][t8 + 4096]); } while (0)

    f32x16 acc[4][2];               // 4 mtiles x 2 ntiles of 32x32
#pragma unroll
    for (int i = 0; i < 4; ++i)
#pragma unroll
        for (int j = 0; j < 2; ++j)
#pragma unroll
            for (int r = 0; r < 16; ++r)
                acc[i][j][r] = 0.f;

    int rr = lane & 31;             // row within 32x32 tile
    int kg = lane >> 5;             // k-group (8 elems)
    // read-side v2: slot(ks) = (ks*2+kg) ^ ((lane>>1)&3) ^ ((lane>>3)&3)
    // (tile bases are multiples of 32 -> row-dependence reduces to lane bits)
    int q12 = ((lane >> 1) & 3) ^ ((lane >> 3) & 3);

    f16x8 a_[4][2], b_[2][2];

#define READ_A(ks) _Pragma("unroll")                                           \
    for (int i = 0; i < 4; ++i) {                                              \
        int row = wr * 128 + i * 32 + rr;                                      \
        int ko = ((((ks) * 2 + kg) ^ q12) * 8);                                \
        a_[i][0] = *(const f16x8*)(&lds[cur][0][row * BK + ko]);               \
        a_[i][1] = *(const f16x8*)(&lds[cur][1][row * BK + ko]);               \
    }
#define READ_B(ks) _Pragma("unroll")                                           \
    for (int j = 0; j < 2; ++j) {                                              \
        int row = wc * 64 + j * 32 + rr;                                       \
        int ko = ((((ks) * 2 + kg) ^ q12) * 8);                                \
        b_[j][0] = *(const f16x8*)(&lds[cur][2][row * BK + ko]);               \
        b_[j][1] = *(const f16x8*)(&lds[cur][3][row * BK + ko]);               \
    }
#define MFMA_STEP() _Pragma("unroll")                                          \
    for (int i = 0; i < 4; ++i) _Pragma("unroll")                              \
        for (int j = 0; j < 2; ++j) {                                          \
            f32x16 c = acc[i][j];                                              \
            c = mfma32(a_[i][0], b_[j][1], c);   /* Ah·Bl */                   \
            c = mfma32(a_[i][1], b_[j][0], c);   /* Al·Bh */                   \
            c = mfma32(a_[i][0], b_[j][0], c);   /* Ah·Bh */                   \
            acc[i][j] = c;                                                     \
        }

    // prologue: tile 0 -> buf 0 (8 loads)
    SPAIR(0, 0, gAh, 0); SPAIR(0, 1, gAl, 0);
    SPAIR(0, 2, gBh, 0); SPAIR(0, 3, gBl, 0);

    for (int kt = 0; kt < KT_N; ++kt) {
        int cur = kt & 1, nxt = 1 - cur;
        bool pre = (kt < KT_N - 1);
        __builtin_amdgcn_sched_barrier(0);
        asm volatile("s_waitcnt vmcnt(0)" ::: "memory");
        __builtin_amdgcn_s_barrier();
        __builtin_amdgcn_sched_barrier(0);

        READ_B(0);
        READ_A(0);
        if (pre) { SPAIR(nxt, 0, gAh, kt + 1); SPAIR(nxt, 1, gAl, kt + 1); }
        __builtin_amdgcn_s_setprio(1);
        MFMA_STEP();                 // k-step 0 (k 0..15)
        __builtin_amdgcn_s_setprio(0);
        READ_A(1);
        READ_B(1);
        if (pre) { SPAIR(nxt, 2, gBh, kt + 1); SPAIR(nxt, 3, gBl, kt + 1); }
        __builtin_amdgcn_s_setprio(1);
        MFMA_STEP();                 // k-step 1 (k 16..31)
        __builtin_amdgcn_s_setprio(0);
    }

    // epilogue: 32x32 D layout [m74/m101, r8-refverified]: col=lane&31,
    // row = (reg&3) + 8*(reg>>2) + 4*(lane>>5)
    int n0 = bn * BN;
    float* outp; int nb;
    if (n0 < HDIM)            { outp = pc; nb = n0; }
    else if (n0 < 2 * HDIM)   { outp = pa; nb = n0 - HDIM; }
    else                      { outp = ph; nb = n0 - 2 * HDIM; }

#pragma unroll
    for (int i = 0; i < 4; ++i)
#pragma unroll
        for (int j = 0; j < 2; ++j) {
            int mbase = bm * BM + wr * 128 + i * 32 + 4 * kg;
            int nn = nb + wc * 64 + j * 32 + rr;
#pragma unroll
            for (int t = 0; t < 4; ++t)
#pragma unroll
                for (int q = 0; q < 4; ++q)
                    outp[(size_t)(mbase + q + 8 * t) * HDIM + nn] = acc[i][j][t * 4 + q];
        }
#undef SPAIR
#undef READ_A
#undef READ_B
#undef MFMA_STEP
}

// ------------------------- recurrence ------------------------------------
// one thread per (b,j); 65536 threads; depth-16 register prefetch pipeline
// (PF=16: 48 outstanding loads <= 63 vmcnt capacity; PF=32 exceeded it).
// libm transcendentals (r8 measured: fast variants null — BW/latency-bound).
__global__ __launch_bounds__(256) void recur(const float* __restrict__ pc_a,
                                             const float* __restrict__ pa_a,
                                             float* out,
                                             const float* __restrict__ h0,
                                             const float* __restrict__ wc_,
                                             const float* __restrict__ bc_,
                                             const float* __restrict__ wa_,
                                             const float* __restrict__ ba_,
                                             const float* __restrict__ bh_) {
    int idx = blockIdx.x * 256 + threadIdx.x;
    int j = idx & (HDIM - 1);
    float h  = h0[idx];
    float wc = wc_[j], bc = bc_[j];
    float wa = wa_[j], ba = ba_[j];
    float bh = bh_[j];

#define PF 16
    float pc[PF], pa[PF], ph[PF];
#pragma unroll
    for (int u = 0; u < PF; ++u) {
        pc[u] = pc_a[(size_t)u * STRIDE + idx];
        pa[u] = pa_a[(size_t)u * STRIDE + idx];
        ph[u] = out [(size_t)u * STRIDE + idx];
    }

    for (int sb = 0; sb < SEQLEN; sb += PF) {
#pragma unroll
        for (int u = 0; u < PF; ++u) {
            int s = sb + u;
            float vc = pc[u], va = pa[u], vh = ph[u];
            int sp = s + PF; sp = (sp < SEQLEN) ? sp : (SEQLEN - 1);
            pc[u] = pc_a[(size_t)sp * STRIDE + idx];
            pa[u] = pa_a[(size_t)sp * STRIDE + idx];
            ph[u] = out [(size_t)sp * STRIDE + idx];

            float zc = (vc + bc) + wc * h;
            float za = (va + ba) + wa * h;
            float c  = 1.0f / (1.0f + expf(-zc));
            float a  = 1.0f + tanhf(za);
            float ht = tanhf((vh + bh) + a * h);
            h = c * h + (1.0f - c) * ht;
            out[(size_t)s * STRIDE + idx] = h;
        }
    }
    out[(size_t)SEQLEN * STRIDE + idx] = h;   // hn
}

// --------------------------- launch --------------------------------------
extern "C" void kernel_launch(void* const* d_in, const int* in_sizes, int n_in,
                              void* d_out, int out_size, void* d_ws, size_t ws_size,
                              hipStream_t stream) {
    const float* x_seq = (const float*)d_in[0];
    const float* h0    = (const float*)d_in[1];
    const float* U_c   = (const float*)d_in[2];
    const float* w_c   = (const float*)d_in[3];
    const float* b_c   = (const float*)d_in[4];
    const float* U_a   = (const float*)d_in[5];
    const float* w_a   = (const float*)d_in[6];
    const float* b_a   = (const float*)d_in[7];
    const float* U_h   = (const float*)d_in[8];
    const float* b_h   = (const float*)d_in[9];
    float* out = (float*)d_out;

    char* ws = (char*)d_ws;
    const size_t MB = 1024 * 1024;
    float*    ws_pc = (float*)ws;                        // 128 MB
    float*    ws_pa = (float*)(ws + 128 * MB);           // 128 MB
    _Float16* x_hi  = (_Float16*)(ws + 256 * MB);        // 32 MB
    _Float16* x_lo  = (_Float16*)(ws + 288 * MB);        // 32 MB
    _Float16* u_hi  = (_Float16*)(ws + 320 * MB);        // 3 MB
    _Float16* u_lo  = (_Float16*)(ws + 323 * MB);        // 3 MB

    cvt_all<<<dim3((XTHREADS + UTHREADS) / 256), dim3(256), 0, stream>>>(
        x_seq, U_c, U_a, U_h, x_hi, x_lo, u_hi, u_lo);
    gemm_f16x2<<<dim3(GRID), dim3(512), 0, stream>>>(
        x_hi, x_lo, u_hi, u_lo, ws_pc, ws_pa, out);
    recur<<<dim3(STRIDE / 256), dim3(256), 0, stream>>>(ws_pc, ws_pa, out, h0,
                                                        w_c, b_c, w_a, b_a, b_h);
}